// Round 5
// baseline (251.342 us; speedup 1.0000x reference)
//
#include <hip/hip_runtime.h>
#include <math.h>

#define T_STEPS 9
#define D_IN    512
#define HID     64
#define G4      256   // 4*HID
#define BPB     8     // batches per block
#define MTP     80    // padded tile rows (72 real = BPB*T_STEPS, +8 pad)

typedef short  short8 __attribute__((ext_vector_type(8)));
typedef float  f32x4  __attribute__((ext_vector_type(4)));
typedef unsigned int uint;
typedef unsigned short ushort;

// ---------------------------------------------------------------------------
__device__ __forceinline__ ushort f2bf(float f) {
    uint u = __float_as_uint(f);
    u = (u + 0x7FFFu + ((u >> 16) & 1u)) >> 16;   // RNE
    return (ushort)u;
}
__device__ __forceinline__ float fsig(float x) {
    return 1.0f / (1.0f + __expf(-x));
}
__device__ __forceinline__ float ftanh(float x) {
    float t = __expf(-2.0f * fabsf(x));
    float r = (1.0f - t) / (1.0f + t);
    return copysignf(r, x);
}

// ---------------------------------------------------------------------------
// Prepass: weights -> bf16 fragment-exact layouts.
// WxT: [k0(16)][qk(4)][n(256)][j(8)]   k = k0*32+qk*8+j   (131072 elems, 256 KB)
// WhT: [kq(8)][n(256)][j(8)]           k = kq*8+j         ( 16384 elems,  32 KB)
__global__ __launch_bounds__(256)
void prep_w(const float* __restrict__ kern, ushort* __restrict__ wxT,
            ushort* __restrict__ whT)
{
    int i = blockIdx.x * 256 + threadIdx.x;
    if (i < 131072) {
        int j  = i & 7;
        int n  = (i >> 3) & 255;
        int qk = (i >> 11) & 3;
        int k0 = i >> 13;
        int k  = k0 * 32 + qk * 8 + j;
        wxT[i] = f2bf(kern[(size_t)k * G4 + n]);
    } else {
        int i2 = i - 131072;
        int j  = i2 & 7;
        int n  = (i2 >> 3) & 255;
        int kq = i2 >> 11;
        whT[i2] = f2bf(kern[(size_t)(D_IN + kq * 8 + j) * G4 + n]);
    }
}

// ---------------------------------------------------------------------------
// Fused LSTM, BPB=8 batches/block, 512 blocks (2/CU), LDS = 7 KB.
// Phase 1: xg GEMM with permuted rows m' = s*8 + b, so the MFMA accumulators
// acc[i][g] (C-layout: row-ofs 4*quad+r) hold xg[step 2i+(quad>=2)][batch
// 4*(quad&1)+r][gate g][unit u=w*16+lane15] — phase 2 reads them directly.
// Phase 2: 9-step recurrence; c-state alternates quad-pairs via shfl_xor(32);
// h round-trips through a 2 KB LDS A-layout buffer with step-parity rows.
__global__ __launch_bounds__(256, 2)
void lstm_fused(const float* __restrict__ x, const ushort* __restrict__ wxT,
                const ushort* __restrict__ whT, const float* __restrict__ bias,
                float* __restrict__ out)
{
    __shared__ ushort sA[4 * MTP * 8];   // 5 KB  [qk][m'][j]
    __shared__ ushort sH[8 * 16 * 8];    // 2 KB  [kq][m(16: parity halves)][j]

    const int t = threadIdx.x;
    const int w = t >> 6, l = t & 63;
    const int lane15 = l & 15, quad = l >> 4;
    const int u = w * 16 + lane15;

    // ---- Wh B-fragments -> registers (coalesced 16-lane runs, L2-hot)
    short8 whF[4][2];
    #pragma unroll
    for (int g = 0; g < 4; ++g)
        #pragma unroll
        for (int kh = 0; kh < 2; ++kh)
            whF[g][kh] = *(const short8*)&whT[(size_t)((kh * 4 + quad) * 256 + g * 64 + u) * 8];

    // ---- zero sH (h_0 = 0; also the step-0 "stale half" must be zero)
    ((uint2*)sH)[t] = (uint2){0u, 0u};

    // =======================  Phase 1: xg GEMM  ===========================
    const float* xblk = x + (size_t)blockIdx.x * (BPB * T_STEPS) * D_IN;
    const int mhalf = t >> 1, kh_a = t & 1;        // half-row id, k-half
    const bool ld = (mhalf < BPB * T_STEPS);       // 72 real rows
    const bool zr = (!ld && mhalf < MTP);          // 8 pad rows -> zeros
    const int b_ = mhalf & 7, s_ = mhalf >> 3;     // m' = s*8 + b
    const float* pA = xblk + (size_t)(b_ * T_STEPS + s_) * D_IN + kh_a * 16;

    float4 rA[4];
    if (ld) {
        #pragma unroll
        for (int q = 0; q < 4; ++q) rA[q] = ((const float4*)pA)[q];
    }

    f32x4 acc[5][4];
    #pragma unroll
    for (int i = 0; i < 5; ++i)
        #pragma unroll
        for (int g = 0; g < 4; ++g)
            acc[i][g] = (f32x4){0.f, 0.f, 0.f, 0.f};

    for (int k0 = 0; k0 < 16; ++k0) {
        __syncthreads();   // previous chunk's sA readers done
        if (ld) {
            uint4 lo, hi;
            lo.x = f2bf(rA[0].x) | ((uint)f2bf(rA[0].y) << 16);
            lo.y = f2bf(rA[0].z) | ((uint)f2bf(rA[0].w) << 16);
            lo.z = f2bf(rA[1].x) | ((uint)f2bf(rA[1].y) << 16);
            lo.w = f2bf(rA[1].z) | ((uint)f2bf(rA[1].w) << 16);
            hi.x = f2bf(rA[2].x) | ((uint)f2bf(rA[2].y) << 16);
            hi.y = f2bf(rA[2].z) | ((uint)f2bf(rA[2].w) << 16);
            hi.z = f2bf(rA[3].x) | ((uint)f2bf(rA[3].y) << 16);
            hi.w = f2bf(rA[3].z) | ((uint)f2bf(rA[3].w) << 16);
            *(uint4*)&sA[((kh_a * 2 + 0) * MTP + mhalf) * 8] = lo;
            *(uint4*)&sA[((kh_a * 2 + 1) * MTP + mhalf) * 8] = hi;
        } else if (zr) {
            uint4 z = {0u, 0u, 0u, 0u};
            *(uint4*)&sA[((kh_a * 2 + 0) * MTP + mhalf) * 8] = z;
            *(uint4*)&sA[((kh_a * 2 + 1) * MTP + mhalf) * 8] = z;
        }
        __syncthreads();   // sA chunk visible

        // prefetch next chunk's x (overlaps the MFMA block below)
        if (ld && k0 < 15) {
            const float4* nA = (const float4*)(pA + (k0 + 1) * 32);
            #pragma unroll
            for (int q = 0; q < 4; ++q) rA[q] = nA[q];
        }

        // Wx B-fragments straight from global (wxT is fragment-exact, L2-hot)
        const ushort* wxc = wxT + (size_t)(k0 * 4 + quad) * 256 * 8;
        short8 bF[4];
        #pragma unroll
        for (int g = 0; g < 4; ++g)
            bF[g] = *(const short8*)&wxc[(size_t)(g * 64 + u) * 8];

        #pragma unroll
        for (int i = 0; i < 5; ++i) {
            short8 aF = *(const short8*)&sA[(quad * MTP + i * 16 + lane15) * 8];
            #pragma unroll
            for (int g = 0; g < 4; ++g)
                acc[i][g] = __builtin_amdgcn_mfma_f32_16x16x32_bf16(aF, bF[g], acc[i][g], 0, 0, 0);
        }
    }

    // =======================  Phase 2: recurrence  ========================
    float bia[4];
    bia[0] = bias[u];
    bia[1] = bias[64 + u];
    bia[2] = bias[128 + u] + 1.0f;       // FORGET_BIAS folded
    bia[3] = bias[192 + u];

    float cst[4] = {0.f, 0.f, 0.f, 0.f};
    const int b0 = blockIdx.x * BPB;

    for (int s = 0; s < T_STEPS; ++s) {
        const int  i = s >> 1;
        const int  p = s & 1;
        const bool active = ((quad >> 1) == p);   // quads {2p, 2p+1} hold step s
        const int  bofs = (quad & 1) * 4;         // batch = bofs + r

        // gates = xg (from accumulators) + bias
        f32x4 g4[4];
        #pragma unroll
        for (int g = 0; g < 4; ++g)
            #pragma unroll
            for (int r = 0; r < 4; ++r)
                g4[g][r] = acc[i][g][r] + bia[g];

        // h_{s-1} fragments (A-layout; rows 8p..8p+7 hold h_{s-1}, other half
        // is h_{s-2}/zero and only feeds inactive C rows)
        short8 aF[2];
        #pragma unroll
        for (int kh = 0; kh < 2; ++kh)
            aF[kh] = *(const short8*)&sH[((kh * 4 + quad) * 16 + lane15) * 8];

        #pragma unroll
        for (int g = 0; g < 4; ++g)
            #pragma unroll
            for (int kh = 0; kh < 2; ++kh)
                g4[g] = __builtin_amdgcn_mfma_f32_16x16x32_bf16(aF[kh], whF[g][kh], g4[g], 0, 0, 0);

        __syncthreads();   // all sH reads of this step done (also phase-entry sync at s=0)

        const int wrow = 8 * ((s + 1) & 1);   // rows for h_s = next step's parity
        #pragma unroll
        for (int r = 0; r < 4; ++r) {
            float cp = __shfl_xor(cst[r], 32);   // partner quad's c_{s-1} (all lanes)
            if (active) {
                float ii = fsig(g4[0][r]);
                float jj = ftanh(g4[1][r]);
                float ff = fsig(g4[2][r]);
                float oo = fsig(g4[3][r]);
                float c  = ff * cp + ii * jj;
                cst[r] = c;
                float h = oo * ftanh(c);
                int bb = bofs + r;
                out[((size_t)(b0 + bb) * T_STEPS + s) * HID + u] = h;
                sH[((u >> 3) * 16 + wrow + bb) * 8 + (u & 7)] = f2bf(h);
            }
        }
        __syncthreads();   // h_s visible before next step's reads
    }
}

// ---------------------------------------------------------------------------
extern "C" void kernel_launch(void* const* d_in, const int* in_sizes, int n_in,
                              void* d_out, int out_size, void* d_ws, size_t ws_size,
                              hipStream_t stream)
{
    const float* x    = (const float*)d_in[0];
    const float* kern = (const float*)d_in[1];
    const float* bias = (const float*)d_in[2];
    float* out = (float*)d_out;

    const int B = in_sizes[0] / (T_STEPS * D_IN);   // 4096

    ushort* wxT = (ushort*)d_ws;                    // 256 KB
    ushort* whT = (ushort*)((char*)d_ws + 262144);  // 32 KB

    prep_w<<<576, 256, 0, stream>>>(kern, wxT, whT);
    lstm_fused<<<B / BPB, 256, 0, stream>>>(x, wxT, whT, bias, out);
}

// Round 6
// 135.391 us; speedup vs baseline: 1.8564x; 1.8564x over previous
//
#include <hip/hip_runtime.h>
#include <math.h>

#define T_STEPS 9
#define D_IN    512
#define HID     64
#define G4      256   // 4*HID
#define BPB     8     // batches per block
#define MTP     80    // padded tile rows (72 real = BPB*T_STEPS, +8 pad)

typedef short  short8 __attribute__((ext_vector_type(8)));
typedef float  f32x4  __attribute__((ext_vector_type(4)));
typedef unsigned int uint;
typedef unsigned short ushort;

// ---------------------------------------------------------------------------
__device__ __forceinline__ ushort f2bf(float f) {
    uint u = __float_as_uint(f);
    u = (u + 0x7FFFu + ((u >> 16) & 1u)) >> 16;   // RNE
    return (ushort)u;
}
__device__ __forceinline__ float fsig(float x) {
    return 1.0f / (1.0f + __expf(-x));
}
__device__ __forceinline__ float ftanh(float x) {
    float t = __expf(-2.0f * fabsf(x));
    float r = (1.0f - t) / (1.0f + t);
    return copysignf(r, x);
}

// ---------------------------------------------------------------------------
// Prepass: weights -> bf16 fragment-exact layouts.
// WxT: [k0(16)][qk(4)][n(256)][j(8)]   k = k0*32+qk*8+j   (131072 elems, 256 KB)
// WhT: [kq(8)][n(256)][j(8)]           k = kq*8+j         ( 16384 elems,  32 KB)
__global__ __launch_bounds__(256)
void prep_w(const float* __restrict__ kern, ushort* __restrict__ wxT,
            ushort* __restrict__ whT)
{
    int i = blockIdx.x * 256 + threadIdx.x;
    if (i < 131072) {
        int j  = i & 7;
        int n  = (i >> 3) & 255;
        int qk = (i >> 11) & 3;
        int k0 = i >> 13;
        int k  = k0 * 32 + qk * 8 + j;
        wxT[i] = f2bf(kern[(size_t)k * G4 + n]);
    } else {
        int i2 = i - 131072;
        int j  = i2 & 7;
        int n  = (i2 >> 3) & 255;
        int kq = i2 >> 11;
        whT[i2] = f2bf(kern[(size_t)(D_IN + kq * 8 + j) * G4 + n]);
    }
}

// ---------------------------------------------------------------------------
// Fused LSTM, BPB=8 batches/block, 512 blocks (2/CU), LDS = 7 KB.
// Phase 1: xg GEMM with permuted rows m' = s*8 + b, so the MFMA accumulators
// acc[i][g] (C-layout: row-ofs 4*quad+r) hold xg[step 2i+(quad>=2)][batch
// 4*(quad&1)+r][gate g][unit u=w*16+lane15] — phase 2 reads them directly.
// Phase 2: FULLY UNROLLED 9-step recurrence (R5 bug: runtime acc[] index
// forced the accumulators into scratch -> 670 MB of spill traffic).
// c-state alternates quad-pairs via shfl_xor(32); h round-trips through a
// 2 KB LDS A-layout buffer with step-parity rows.
__global__ __launch_bounds__(256, 2)
void lstm_fused(const float* __restrict__ x, const ushort* __restrict__ wxT,
                const ushort* __restrict__ whT, const float* __restrict__ bias,
                float* __restrict__ out)
{
    __shared__ ushort sA[4 * MTP * 8];   // 5 KB  [qk][m'][j]
    __shared__ ushort sH[8 * 16 * 8];    // 2 KB  [kq][m(16: parity halves)][j]

    const int t = threadIdx.x;
    const int w = t >> 6, l = t & 63;
    const int lane15 = l & 15, quad = l >> 4;
    const int u = w * 16 + lane15;

    // ---- Wh B-fragments -> registers (coalesced 16-lane runs, L2-hot)
    short8 whF[4][2];
    #pragma unroll
    for (int g = 0; g < 4; ++g)
        #pragma unroll
        for (int kh = 0; kh < 2; ++kh)
            whF[g][kh] = *(const short8*)&whT[(size_t)((kh * 4 + quad) * 256 + g * 64 + u) * 8];

    // ---- zero sH (h_0 = 0; also the step-0 "stale half" must be zero)
    ((uint2*)sH)[t] = (uint2){0u, 0u};

    // =======================  Phase 1: xg GEMM  ===========================
    const float* xblk = x + (size_t)blockIdx.x * (BPB * T_STEPS) * D_IN;
    const int mhalf = t >> 1, kh_a = t & 1;        // half-row id, k-half
    const bool ld = (mhalf < BPB * T_STEPS);       // 72 real rows
    const bool zr = (!ld && mhalf < MTP);          // 8 pad rows -> zeros
    const int b_ = mhalf & 7, s_ = mhalf >> 3;     // m' = s*8 + b
    const float* pA = xblk + (size_t)(b_ * T_STEPS + s_) * D_IN + kh_a * 16;

    float4 rA[4];
    if (ld) {
        #pragma unroll
        for (int q = 0; q < 4; ++q) rA[q] = ((const float4*)pA)[q];
    }

    f32x4 acc[5][4];
    #pragma unroll
    for (int i = 0; i < 5; ++i)
        #pragma unroll
        for (int g = 0; g < 4; ++g)
            acc[i][g] = (f32x4){0.f, 0.f, 0.f, 0.f};

    for (int k0 = 0; k0 < 16; ++k0) {
        __syncthreads();   // previous chunk's sA readers done
        if (ld) {
            uint4 lo, hi;
            lo.x = f2bf(rA[0].x) | ((uint)f2bf(rA[0].y) << 16);
            lo.y = f2bf(rA[0].z) | ((uint)f2bf(rA[0].w) << 16);
            lo.z = f2bf(rA[1].x) | ((uint)f2bf(rA[1].y) << 16);
            lo.w = f2bf(rA[1].z) | ((uint)f2bf(rA[1].w) << 16);
            hi.x = f2bf(rA[2].x) | ((uint)f2bf(rA[2].y) << 16);
            hi.y = f2bf(rA[2].z) | ((uint)f2bf(rA[2].w) << 16);
            hi.z = f2bf(rA[3].x) | ((uint)f2bf(rA[3].y) << 16);
            hi.w = f2bf(rA[3].z) | ((uint)f2bf(rA[3].w) << 16);
            *(uint4*)&sA[((kh_a * 2 + 0) * MTP + mhalf) * 8] = lo;
            *(uint4*)&sA[((kh_a * 2 + 1) * MTP + mhalf) * 8] = hi;
        } else if (zr) {
            uint4 z = {0u, 0u, 0u, 0u};
            *(uint4*)&sA[((kh_a * 2 + 0) * MTP + mhalf) * 8] = z;
            *(uint4*)&sA[((kh_a * 2 + 1) * MTP + mhalf) * 8] = z;
        }
        __syncthreads();   // sA chunk visible

        // prefetch next chunk's x (overlaps the MFMA block below)
        if (ld && k0 < 15) {
            const float4* nA = (const float4*)(pA + (k0 + 1) * 32);
            #pragma unroll
            for (int q = 0; q < 4; ++q) rA[q] = nA[q];
        }

        // Wx B-fragments straight from global (wxT is fragment-exact, L2-hot)
        const ushort* wxc = wxT + (size_t)(k0 * 4 + quad) * 256 * 8;
        short8 bF[4];
        #pragma unroll
        for (int g = 0; g < 4; ++g)
            bF[g] = *(const short8*)&wxc[(size_t)(g * 64 + u) * 8];

        #pragma unroll
        for (int i = 0; i < 5; ++i) {
            short8 aF = *(const short8*)&sA[(quad * MTP + i * 16 + lane15) * 8];
            #pragma unroll
            for (int g = 0; g < 4; ++g)
                acc[i][g] = __builtin_amdgcn_mfma_f32_16x16x32_bf16(aF, bF[g], acc[i][g], 0, 0, 0);
        }
    }

    // =======================  Phase 2: recurrence  ========================
    float bia[4];
    bia[0] = bias[u];
    bia[1] = bias[64 + u];
    bia[2] = bias[128 + u] + 1.0f;       // FORGET_BIAS folded
    bia[3] = bias[192 + u];

    float cst[4] = {0.f, 0.f, 0.f, 0.f};
    const int b0 = blockIdx.x * BPB;

    #pragma unroll                         // <-- the fix: i,p,wrow compile-time
    for (int s = 0; s < T_STEPS; ++s) {
        const int  i = s >> 1;
        const int  p = s & 1;
        const bool active = ((quad >> 1) == p);   // quads {2p, 2p+1} hold step s
        const int  bofs = (quad & 1) * 4;         // batch = bofs + r

        // gates = xg (from accumulators) + bias
        f32x4 g4[4];
        #pragma unroll
        for (int g = 0; g < 4; ++g)
            #pragma unroll
            for (int r = 0; r < 4; ++r)
                g4[g][r] = acc[i][g][r] + bia[g];

        // h_{s-1} fragments (A-layout; rows 8p..8p+7 hold h_{s-1}, other half
        // is h_{s-2}/zero and only feeds inactive C rows)
        short8 aF[2];
        #pragma unroll
        for (int kh = 0; kh < 2; ++kh)
            aF[kh] = *(const short8*)&sH[((kh * 4 + quad) * 16 + lane15) * 8];

        #pragma unroll
        for (int g = 0; g < 4; ++g)
            #pragma unroll
            for (int kh = 0; kh < 2; ++kh)
                g4[g] = __builtin_amdgcn_mfma_f32_16x16x32_bf16(aF[kh], whF[g][kh], g4[g], 0, 0, 0);

        __syncthreads();   // all sH reads of this step done (also phase-entry sync at s=0)

        const int wrow = 8 * ((s + 1) & 1);   // rows for h_s = next step's parity
        #pragma unroll
        for (int r = 0; r < 4; ++r) {
            float cp = __shfl_xor(cst[r], 32);   // partner quad's c_{s-1} (all lanes)
            if (active) {
                float ii = fsig(g4[0][r]);
                float jj = ftanh(g4[1][r]);
                float ff = fsig(g4[2][r]);
                float oo = fsig(g4[3][r]);
                float c  = ff * cp + ii * jj;
                cst[r] = c;
                float h = oo * ftanh(c);
                int bb = bofs + r;
                out[((size_t)(b0 + bb) * T_STEPS + s) * HID + u] = h;
                sH[((u >> 3) * 16 + wrow + bb) * 8 + (u & 7)] = f2bf(h);
            }
        }
        __syncthreads();   // h_s visible before next step's reads
    }
}

// ---------------------------------------------------------------------------
extern "C" void kernel_launch(void* const* d_in, const int* in_sizes, int n_in,
                              void* d_out, int out_size, void* d_ws, size_t ws_size,
                              hipStream_t stream)
{
    const float* x    = (const float*)d_in[0];
    const float* kern = (const float*)d_in[1];
    const float* bias = (const float*)d_in[2];
    float* out = (float*)d_out;

    const int B = in_sizes[0] / (T_STEPS * D_IN);   // 4096

    ushort* wxT = (ushort*)d_ws;                    // 256 KB
    ushort* whT = (ushort*)((char*)d_ws + 262144);  // 32 KB

    prep_w<<<576, 256, 0, stream>>>(kern, wxT, whT);
    lstm_fused<<<B / BPB, 256, 0, stream>>>(x, wxT, whT, bias, out);
}

// Round 7
// 134.745 us; speedup vs baseline: 1.8653x; 1.0048x over previous
//
#include <hip/hip_runtime.h>
#include <math.h>

#define T_STEPS 9
#define D_IN    512
#define HID     64
#define G4      256   // 4*HID
#define BPB     8     // batches per block
#define MTP     80    // padded tile rows (72 real = BPB*T_STEPS, +8 pad)

typedef short  short8 __attribute__((ext_vector_type(8)));
typedef float  f32x4  __attribute__((ext_vector_type(4)));
typedef unsigned int uint;
typedef unsigned short ushort;

// ---------------------------------------------------------------------------
__device__ __forceinline__ ushort f2bf(float f) {
    uint u = __float_as_uint(f);
    u = (u + 0x7FFFu + ((u >> 16) & 1u)) >> 16;   // RNE
    return (ushort)u;
}
__device__ __forceinline__ float fsig(float x) {
    return 1.0f / (1.0f + __expf(-x));
}
__device__ __forceinline__ float ftanh(float x) {
    float t = __expf(-2.0f * fabsf(x));
    float r = (1.0f - t) / (1.0f + t);
    return copysignf(r, x);
}
// XOR-swizzled sA slot index (ushort units). Row swizzle spreads the
// stride-2-row writer pattern over 8 bank-groups (was 9-way conflict).
__device__ __forceinline__ int saidx(int qk, int row) {
    return (qk * MTP + (row ^ ((row >> 3) & 7))) * 8;
}

// ---------------------------------------------------------------------------
// Prepass: weights -> bf16 fragment-exact layouts.
// WxT: [k0(16)][qk(4)][n(256)][j(8)]   k = k0*32+qk*8+j   (131072 elems, 256 KB)
// WhT: [kq(8)][n(256)][j(8)]           k = kq*8+j         ( 16384 elems,  32 KB)
__global__ __launch_bounds__(256)
void prep_w(const float* __restrict__ kern, ushort* __restrict__ wxT,
            ushort* __restrict__ whT)
{
    int i = blockIdx.x * 256 + threadIdx.x;
    if (i < 131072) {
        int j  = i & 7;
        int n  = (i >> 3) & 255;
        int qk = (i >> 11) & 3;
        int k0 = i >> 13;
        int k  = k0 * 32 + qk * 8 + j;
        wxT[i] = f2bf(kern[(size_t)k * G4 + n]);
    } else {
        int i2 = i - 131072;
        int j  = i2 & 7;
        int n  = (i2 >> 3) & 255;
        int kq = i2 >> 11;
        whT[i2] = f2bf(kern[(size_t)(D_IN + kq * 8 + j) * G4 + n]);
    }
}

// ---------------------------------------------------------------------------
// Fused LSTM, BPB=8, 512 blocks (2/CU), deep-pipelined phase-1 K-loop:
// fully unrolled; sA double-buffered (ONE barrier/chunk); x prefetch
// distance 2 (regs); bF (Wx frags) prefetch distance 1; whF loaded at
// phase-2 entry. Phase 2 = R6's verified parity recurrence.
__global__ __launch_bounds__(256, 2)
void lstm_fused(const float* __restrict__ x, const ushort* __restrict__ wxT,
                const ushort* __restrict__ whT, const float* __restrict__ bias,
                float* __restrict__ out)
{
    __shared__ ushort sA[2][4 * MTP * 8];  // 2 x 5 KB, [qk][row^swz][j]
    __shared__ ushort sH[8 * 16 * 8];      // 2 KB, [kq][m(16: parity halves)][j]

    const int t = threadIdx.x;
    const int w = t >> 6, l = t & 63;
    const int lane15 = l & 15, quad = l >> 4;
    const int u = w * 16 + lane15;

    // ---- loader mapping: lanes 0..35 of EVERY wave stage x (balanced).
    const bool isld = (l < 36);
    const int lrow = 2 * l + (w >> 1);    // tile row m' = s*8+b, in [0,72)
    const int lkh  = w & 1;               // k-half (16 floats)
    const int lb = lrow & 7, ls = lrow >> 3;
    const float* xblk = x + (size_t)blockIdx.x * (BPB * T_STEPS) * D_IN;
    const float* pA = xblk + (size_t)(lb * T_STEPS + ls) * D_IN + lkh * 16;

    // ---- prologue: issue x loads for chunks 0,1,2; zero pads + sH
    float4 r0[4], ra[2][4];
    if (isld) {
        #pragma unroll
        for (int q = 0; q < 4; ++q) r0[q]    = ((const float4*)pA)[q];
        #pragma unroll
        for (int q = 0; q < 4; ++q) ra[1][q] = ((const float4*)(pA + 32))[q];
        #pragma unroll
        for (int q = 0; q < 4; ++q) ra[0][q] = ((const float4*)(pA + 64))[q];
    }
    if (t < 64) {   // zero pad rows 72..79 (both buffers; swizzle maps set to itself)
        int buf = t >> 5, slot = t & 31;
        int qk = slot >> 3, row = 72 + (slot & 7);
        uint4 z = {0u, 0u, 0u, 0u};
        *(uint4*)&sA[buf][(qk * MTP + row) * 8] = z;
    }
    ((uint2*)sH)[t] = (uint2){0u, 0u};

    // write chunk 0 into sA[0]
    if (isld) {
        uint4 lo, hi;
        lo.x = f2bf(r0[0].x) | ((uint)f2bf(r0[0].y) << 16);
        lo.y = f2bf(r0[0].z) | ((uint)f2bf(r0[0].w) << 16);
        lo.z = f2bf(r0[1].x) | ((uint)f2bf(r0[1].y) << 16);
        lo.w = f2bf(r0[1].z) | ((uint)f2bf(r0[1].w) << 16);
        hi.x = f2bf(r0[2].x) | ((uint)f2bf(r0[2].y) << 16);
        hi.y = f2bf(r0[2].z) | ((uint)f2bf(r0[2].w) << 16);
        hi.z = f2bf(r0[3].x) | ((uint)f2bf(r0[3].y) << 16);
        hi.w = f2bf(r0[3].z) | ((uint)f2bf(r0[3].w) << 16);
        *(uint4*)&sA[0][saidx(lkh * 2 + 0, lrow)] = lo;
        *(uint4*)&sA[0][saidx(lkh * 2 + 1, lrow)] = hi;
    }

    // bF prologue: chunk 0
    short8 bFb[2][4];
    {
        const ushort* wxc = wxT + (size_t)(0 * 4 + quad) * 256 * 8;
        #pragma unroll
        for (int g = 0; g < 4; ++g)
            bFb[0][g] = *(const short8*)&wxc[(size_t)(g * 64 + u) * 8];
    }

    f32x4 acc[5][4];
    #pragma unroll
    for (int i = 0; i < 5; ++i)
        #pragma unroll
        for (int g = 0; g < 4; ++g)
            acc[i][g] = (f32x4){0.f, 0.f, 0.f, 0.f};

    // =======================  Phase 1: pipelined K-loop  ==================
    #pragma unroll
    for (int k = 0; k < 16; ++k) {
        __syncthreads();   // sA[k&1] (written last iter / prologue) visible

        // prefetch next chunk's bF (L2-hot wxT)
        if (k < 15) {
            const ushort* wxc = wxT + (size_t)((k + 1) * 4 + quad) * 256 * 8;
            #pragma unroll
            for (int g = 0; g < 4; ++g)
                bFb[(k + 1) & 1][g] = *(const short8*)&wxc[(size_t)(g * 64 + u) * 8];
        }

        // MFMA on current chunk
        #pragma unroll
        for (int i = 0; i < 5; ++i) {
            short8 aF = *(const short8*)&sA[k & 1][saidx(quad, i * 16 + lane15)];
            #pragma unroll
            for (int g = 0; g < 4; ++g)
                acc[i][g] = __builtin_amdgcn_mfma_f32_16x16x32_bf16(aF, bFb[k & 1][g], acc[i][g], 0, 0, 0);
        }

        // stage chunk k+1 into the other buffer; refill its register buffer
        // with chunk k+3 (prefetch distance 2)
        if (k < 15 && isld) {
            float4 v0 = ra[(k + 1) & 1][0], v1 = ra[(k + 1) & 1][1];
            float4 v2 = ra[(k + 1) & 1][2], v3 = ra[(k + 1) & 1][3];
            uint4 lo, hi;
            lo.x = f2bf(v0.x) | ((uint)f2bf(v0.y) << 16);
            lo.y = f2bf(v0.z) | ((uint)f2bf(v0.w) << 16);
            lo.z = f2bf(v1.x) | ((uint)f2bf(v1.y) << 16);
            lo.w = f2bf(v1.z) | ((uint)f2bf(v1.w) << 16);
            hi.x = f2bf(v2.x) | ((uint)f2bf(v2.y) << 16);
            hi.y = f2bf(v2.z) | ((uint)f2bf(v2.w) << 16);
            hi.z = f2bf(v3.x) | ((uint)f2bf(v3.y) << 16);
            hi.w = f2bf(v3.z) | ((uint)f2bf(v3.w) << 16);
            *(uint4*)&sA[(k + 1) & 1][saidx(lkh * 2 + 0, lrow)] = lo;
            *(uint4*)&sA[(k + 1) & 1][saidx(lkh * 2 + 1, lrow)] = hi;
            if (k < 13) {
                const float4* np = (const float4*)(pA + (k + 3) * 32);
                #pragma unroll
                for (int q = 0; q < 4; ++q) ra[(k + 1) & 1][q] = np[q];
            }
        }
    }

    // =======================  Phase 2: recurrence  ========================
    // Wh B-fragments -> registers (deferred; phase-1 regs now free)
    short8 whF[4][2];
    #pragma unroll
    for (int g = 0; g < 4; ++g)
        #pragma unroll
        for (int kh = 0; kh < 2; ++kh)
            whF[g][kh] = *(const short8*)&whT[(size_t)((kh * 4 + quad) * 256 + g * 64 + u) * 8];

    float bia[4];
    bia[0] = bias[u];
    bia[1] = bias[64 + u];
    bia[2] = bias[128 + u] + 1.0f;       // FORGET_BIAS folded
    bia[3] = bias[192 + u];

    float cst[4] = {0.f, 0.f, 0.f, 0.f};
    const int b0 = blockIdx.x * BPB;

    #pragma unroll                         // static acc[] indices (R5 lesson)
    for (int s = 0; s < T_STEPS; ++s) {
        const int  i = s >> 1;
        const int  p = s & 1;
        const bool active = ((quad >> 1) == p);   // quads {2p, 2p+1} hold step s
        const int  bofs = (quad & 1) * 4;         // batch = bofs + r

        // gates = xg (from accumulators) + bias
        f32x4 g4[4];
        #pragma unroll
        for (int g = 0; g < 4; ++g)
            #pragma unroll
            for (int r = 0; r < 4; ++r)
                g4[g][r] = acc[i][g][r] + bia[g];

        // h_{s-1} fragments (A-layout; rows 8p..8p+7 hold h_{s-1}; other half
        // only feeds inactive C rows)
        short8 aF[2];
        #pragma unroll
        for (int kh = 0; kh < 2; ++kh)
            aF[kh] = *(const short8*)&sH[((kh * 4 + quad) * 16 + lane15) * 8];

        #pragma unroll
        for (int g = 0; g < 4; ++g)
            #pragma unroll
            for (int kh = 0; kh < 2; ++kh)
                g4[g] = __builtin_amdgcn_mfma_f32_16x16x32_bf16(aF[kh], whF[g][kh], g4[g], 0, 0, 0);

        __syncthreads();   // all sH reads of this step done

        const int wrow = 8 * ((s + 1) & 1);   // rows for h_s = next parity
        #pragma unroll
        for (int r = 0; r < 4; ++r) {
            float cp = __shfl_xor(cst[r], 32);   // partner quad's c_{s-1}
            if (active) {
                float ii = fsig(g4[0][r]);
                float jj = ftanh(g4[1][r]);
                float ff = fsig(g4[2][r]);
                float oo = fsig(g4[3][r]);
                float c  = ff * cp + ii * jj;
                cst[r] = c;
                float h = oo * ftanh(c);
                int bb = bofs + r;
                out[((size_t)(b0 + bb) * T_STEPS + s) * HID + u] = h;
                sH[((u >> 3) * 16 + wrow + bb) * 8 + (u & 7)] = f2bf(h);
            }
        }
        __syncthreads();   // h_s visible before next step's reads
    }
}

// ---------------------------------------------------------------------------
extern "C" void kernel_launch(void* const* d_in, const int* in_sizes, int n_in,
                              void* d_out, int out_size, void* d_ws, size_t ws_size,
                              hipStream_t stream)
{
    const float* x    = (const float*)d_in[0];
    const float* kern = (const float*)d_in[1];
    const float* bias = (const float*)d_in[2];
    float* out = (float*)d_out;

    const int B = in_sizes[0] / (T_STEPS * D_IN);   // 4096

    ushort* wxT = (ushort*)d_ws;                    // 256 KB
    ushort* whT = (ushort*)((char*)d_ws + 262144);  // 32 KB

    prep_w<<<576, 256, 0, stream>>>(kern, wxT, whT);
    lstm_fused<<<B / BPB, 256, 0, stream>>>(x, wxT, whT, bias, out);
}

// Round 8
// 127.894 us; speedup vs baseline: 1.9652x; 1.0536x over previous
//
#include <hip/hip_runtime.h>
#include <math.h>

#define T_STEPS 9
#define D_IN    512
#define HID     64
#define G4      256   // 4*HID
#define BPB     8     // batches per block
#define ROWS    72    // real tile rows = BPB * T_STEPS

typedef short  short8 __attribute__((ext_vector_type(8)));
typedef float  f32x4  __attribute__((ext_vector_type(4)));
typedef unsigned int uint;
typedef unsigned short ushort;

// ---------------------------------------------------------------------------
__device__ __forceinline__ ushort f2bf(float f) {
    uint u = __float_as_uint(f);
    u = (u + 0x7FFFu + ((u >> 16) & 1u)) >> 16;   // RNE
    return (ushort)u;
}
__device__ __forceinline__ float fsig(float x) {
    return 1.0f / (1.0f + __expf(-x));
}
__device__ __forceinline__ float ftanh(float x) {
    float t = __expf(-2.0f * fabsf(x));
    float r = (1.0f - t) / (1.0f + t);
    return copysignf(r, x);
}

// ---------------------------------------------------------------------------
// Prepass: weights -> bf16 fragment-exact layouts.
// WxT: [k0(16)][qk(4)][n(256)][j(8)]   k = k0*32+qk*8+j   (131072 elems, 256 KB)
// WhT: [kq(8)][n(256)][j(8)]           k = kq*8+j         ( 16384 elems,  32 KB)
__global__ __launch_bounds__(256)
void prep_w(const float* __restrict__ kern, ushort* __restrict__ wxT,
            ushort* __restrict__ whT)
{
    int i = blockIdx.x * 256 + threadIdx.x;
    if (i < 131072) {
        int j  = i & 7;
        int n  = (i >> 3) & 255;
        int qk = (i >> 11) & 3;
        int k0 = i >> 13;
        int k  = k0 * 32 + qk * 8 + j;
        wxT[i] = f2bf(kern[(size_t)k * G4 + n]);
    } else {
        int i2 = i - 131072;
        int j  = i2 & 7;
        int n  = (i2 >> 3) & 255;
        int kq = i2 >> 11;
        whT[i2] = f2bf(kern[(size_t)(D_IN + kq * 8 + j) * G4 + n]);
    }
}

// ---------------------------------------------------------------------------
// Fused LSTM. R8 structure: stage the ENTIRE 72x512 x-panel to LDS once
// (36 independent float4 loads/thread, bulk-issued), ONE barrier, then all
// 16 K-chunks barrier-free (pure ds_read+MFMA; compiler pipelines via
// lgkmcnt). sA layout: [row(80)][k swizzled]: byte = row*1024 +
// ((kq ^ (row&7))*16) + (k&7)*2 -> coalesced writes AND conflict-free b128
// fragment reads. Rows 72-79 are pad; their first 2 KB doubles as sH
// (zeroed -> pad C-rows accumulate 0; those C rows are never read).
// Phase 2 = R7's verified parity recurrence.
__global__ __launch_bounds__(256, 2)
void lstm_fused(const float* __restrict__ x, const ushort* __restrict__ wxT,
                const ushort* __restrict__ whT, const float* __restrict__ bias,
                float* __restrict__ out)
{
    __shared__ ushort sAm[80 * 512];          // 80 KB; rows 72-79 = pad + sH
    ushort* const sH = &sAm[72 * 512];        // 2 KB [kq(8)][m(16)][j(8)]

    const int t = threadIdx.x;
    const int w = t >> 6, l = t & 63;
    const int lane15 = l & 15, quad = l >> 4;
    const int u = w * 16 + lane15;

    // ---- zero pad rows 72-79 (8 KB): h_0 = 0 for sH + zero A-pad for i=4
    {
        uint4 z = {0u, 0u, 0u, 0u};
        ((uint4*)&sAm[72 * 512])[t]       = z;
        ((uint4*)&sAm[72 * 512])[t + 256] = z;
    }

    // ---- bF chunk-0 prefetch (issue before the x flood; completes first)
    short8 bFb[2][4];
    {
        const ushort* wxc = wxT + (size_t)(0 * 4 + quad) * 256 * 8;
        #pragma unroll
        for (int g = 0; g < 4; ++g)
            bFb[0][g] = *(const short8*)&wxc[(size_t)(g * 64 + u) * 8];
    }

    // =============  Stage whole x-panel -> LDS (one shot)  ===============
    // float4 id "flat" = h*18*256 + q*256 + t covers 72*128 = 9216 float4s,
    // perfectly coalesced. Tile row permutation: x row r = b*9+s -> tile
    // row = s*8+b. Two batches of 18 keep register pressure bounded.
    const float4* xblk = (const float4*)(x + (size_t)blockIdx.x * (ROWS * D_IN));
    #pragma unroll
    for (int h = 0; h < 2; ++h) {
        float4 v[18];
        #pragma unroll
        for (int q = 0; q < 18; ++q)
            v[q] = xblk[(h * 18 + q) * 256 + t];
        #pragma unroll
        for (int q = 0; q < 18; ++q) {
            int flat = (h * 18 + q) * 256 + t;
            int r    = flat >> 7;          // x row in block (0..71)
            int colq = flat & 127;         // float4 within row
            int b = r / 9, s = r - b * 9;  // magic-div by compiler
            int row = s * 8 + b;           // permuted tile row
            int kq  = colq >> 1;           // 8-elem k-octet index
            int adr = row * 512 + ((kq ^ (row & 7)) << 3) + ((colq & 1) << 2);
            uint2 p;
            p.x = f2bf(v[q].x) | ((uint)f2bf(v[q].y) << 16);
            p.y = f2bf(v[q].z) | ((uint)f2bf(v[q].w) << 16);
            *(uint2*)&sAm[adr] = p;
        }
    }
    __syncthreads();   // the ONLY phase-1 barrier

    // =============  Phase 1 compute: barrier-free K-chunks  ===============
    f32x4 acc[5][4];
    #pragma unroll
    for (int i = 0; i < 5; ++i)
        #pragma unroll
        for (int g = 0; g < 4; ++g)
            acc[i][g] = (f32x4){0.f, 0.f, 0.f, 0.f};

    #pragma unroll
    for (int k = 0; k < 16; ++k) {
        if (k < 15) {   // prefetch next chunk's Wx fragments (L2-hot)
            const ushort* wxc = wxT + (size_t)((k + 1) * 4 + quad) * 256 * 8;
            #pragma unroll
            for (int g = 0; g < 4; ++g)
                bFb[(k + 1) & 1][g] = *(const short8*)&wxc[(size_t)(g * 64 + u) * 8];
        }
        #pragma unroll
        for (int i = 0; i < 5; ++i) {
            int row = i * 16 + lane15;     // i=4 rows 72-79 read zero pad
            short8 aF = *(const short8*)
                &sAm[row * 512 + (((k * 4 + quad) ^ (row & 7)) << 3)];
            #pragma unroll
            for (int g = 0; g < 4; ++g)
                acc[i][g] = __builtin_amdgcn_mfma_f32_16x16x32_bf16(aF, bFb[k & 1][g], acc[i][g], 0, 0, 0);
        }
    }

    // =======================  Phase 2: recurrence  ========================
    short8 whF[4][2];
    #pragma unroll
    for (int g = 0; g < 4; ++g)
        #pragma unroll
        for (int kh = 0; kh < 2; ++kh)
            whF[g][kh] = *(const short8*)&whT[(size_t)((kh * 4 + quad) * 256 + g * 64 + u) * 8];

    float bia[4];
    bia[0] = bias[u];
    bia[1] = bias[64 + u];
    bia[2] = bias[128 + u] + 1.0f;       // FORGET_BIAS folded
    bia[3] = bias[192 + u];

    float cst[4] = {0.f, 0.f, 0.f, 0.f};
    const int b0 = blockIdx.x * BPB;

    #pragma unroll                         // static acc[] indices (R5 lesson)
    for (int s = 0; s < T_STEPS; ++s) {
        const int  i = s >> 1;
        const int  p = s & 1;
        const bool active = ((quad >> 1) == p);   // quads {2p,2p+1} hold step s
        const int  bofs = (quad & 1) * 4;         // batch = bofs + r

        f32x4 g4[4];
        #pragma unroll
        for (int g = 0; g < 4; ++g)
            #pragma unroll
            for (int r = 0; r < 4; ++r)
                g4[g][r] = acc[i][g][r] + bia[g];

        // h_{s-1} fragments (A-layout; rows 8p..8p+7 hold h_{s-1}; other
        // half only feeds inactive C rows; zeros at s=0)
        short8 aF[2];
        #pragma unroll
        for (int kh = 0; kh < 2; ++kh)
            aF[kh] = *(const short8*)&sH[((kh * 4 + quad) * 16 + lane15) * 8];

        #pragma unroll
        for (int g = 0; g < 4; ++g)
            #pragma unroll
            for (int kh = 0; kh < 2; ++kh)
                g4[g] = __builtin_amdgcn_mfma_f32_16x16x32_bf16(aF[kh], whF[g][kh], g4[g], 0, 0, 0);

        __syncthreads();   // all sH (and phase-1 pad) reads done before writes

        const int wrow = 8 * ((s + 1) & 1);   // rows for h_s = next parity
        #pragma unroll
        for (int r = 0; r < 4; ++r) {
            float cp = __shfl_xor(cst[r], 32);   // partner quad's c_{s-1}
            if (active) {
                float ii = fsig(g4[0][r]);
                float jj = ftanh(g4[1][r]);
                float ff = fsig(g4[2][r]);
                float oo = fsig(g4[3][r]);
                float c  = ff * cp + ii * jj;
                cst[r] = c;
                float h = oo * ftanh(c);
                int bb = bofs + r;
                out[((size_t)(b0 + bb) * T_STEPS + s) * HID + u] = h;
                sH[((u >> 3) * 16 + wrow + bb) * 8 + (u & 7)] = f2bf(h);
            }
        }
        __syncthreads();   // h_s visible before next step's reads
    }
}

// ---------------------------------------------------------------------------
extern "C" void kernel_launch(void* const* d_in, const int* in_sizes, int n_in,
                              void* d_out, int out_size, void* d_ws, size_t ws_size,
                              hipStream_t stream)
{
    const float* x    = (const float*)d_in[0];
    const float* kern = (const float*)d_in[1];
    const float* bias = (const float*)d_in[2];
    float* out = (float*)d_out;

    const int B = in_sizes[0] / (T_STEPS * D_IN);   // 4096

    ushort* wxT = (ushort*)d_ws;                    // 256 KB
    ushort* whT = (ushort*)((char*)d_ws + 262144);  // 32 KB

    prep_w<<<576, 256, 0, stream>>>(kern, wxT, whT);
    lstm_fused<<<B / BPB, 256, 0, stream>>>(x, wxT, whT, bias, out);
}